// Round 5
// baseline (9694.598 us; speedup 1.0000x reference)
//
#include <hip/hip_runtime.h>
#include <stdint.h>

typedef unsigned long long u64;
typedef unsigned int u32;
typedef _Float16 f16;
typedef _Float16 half8 __attribute__((ext_vector_type(8)));
typedef float f32x16 __attribute__((ext_vector_type(16)));

#define NTOT 270072
#define TOPK 6000
#define POSTK 1000
#define NW 94              // ceil(6000/64)
#define COMPCAP 8192
#define INVALID_KEY 0xBF800000u

// ---------------------------------------------------------------------------
// Weight transform + fp16x2 split. Input convw OIHW [co][ci][3][3] fp32.
// Output wsp 16B-granule layout: G = (((tap*4 + chunk64)*8 + cb)*2 + half)*256 + co,
// cb = (ci>>3)&7, j = ci&7 inside the granule. conv loads B-fragments straight
// from global (L2-resident, 2.36 MB), so W never touches LDS.
// Weights pre-scaled x128 so lo-halves stay fp16-normal; epilogue /128.
// ---------------------------------------------------------------------------
__global__ __launch_bounds__(256) void wtrans_k(const float* __restrict__ w3,
                                                f16* __restrict__ wsp) {
    int i = blockIdx.x * 256 + threadIdx.x;   // coalesced read of w3
    if (i >= 589824) return;
    float w = w3[i] * 128.0f;
    int tap = i % 9;
    int t2 = i / 9;
    int ci = t2 % 256;
    int co = t2 / 256;
    f16 hi = (f16)w;
    f16 lo = (f16)((w - (float)hi) * 2048.0f);
    int chunk = ci >> 6, cb = (ci >> 3) & 7, j = ci & 7;
    size_t Gh = ((size_t)((tap * 4 + chunk) * 8 + cb) * 2) * 256 + co;
    wsp[Gh * 8 + j] = hi;
    wsp[(Gh + 256) * 8 + j] = lo;   // half=1 plane
}

// ---------------------------------------------------------------------------
// MFMA implicit-GEMM conv (fp16x2 split, 3 products) + fused epilogue.
// Block: 512 thr (8 waves), tile M=128 px (4 h-rows x 32 w) x N=256 co.
// LDS: X halo only, one 64-ci chunk: granule gx = sub*204 + row*34 + col,
//      sub = cb*2+half in [0,16)  -> 16*204*16 B = 52224 B.
// B-fragments are loaded global->VGPR per K-step (coalesced 16B/lane, hits
// L2). Barriers ONLY around the 4 X-stages; 432 MFMAs run barrier-free per
// chunk so the compiler can vmcnt-pipeline the streaming B loads.
// ---------------------------------------------------------------------------
__global__ __launch_bounds__(512, 4) void conv_mfma_k(
    const float* __restrict__ f0, const float* __restrict__ f1,
    const float* __restrict__ f2, const float* __restrict__ f3,
    const float* __restrict__ f4,
    const f16* __restrict__ wsp, const float* __restrict__ convb,
    const float* __restrict__ clsw, const float* __restrict__ clsb,
    const float* __restrict__ bbw, const float* __restrict__ bbb,
    const float* __restrict__ im_info,
    u32* __restrict__ keys, float4* __restrict__ boxes)
{
    const int   Ht[5]      = {12, 24, 48, 96, 192};
    const int   Wt[5]      = {22, 44, 88, 176, 352};
    const int   startB[5]  = {0, 3, 15, 51, 195};
    const int   tilesX[5]  = {1, 2, 3, 6, 11};
    const int   baseA[5]   = {0, 792, 3960, 16632, 67320};
    const float scaleA[5]  = {32.f, 16.f, 8.f, 4.f, 2.f};
    const float strideA[5] = {64.f, 32.f, 16.f, 8.f, 4.f};

    __shared__ __align__(16) char lds[52224];
    f16* Xh = (f16*)lds;                      // 16 sub-planes x 204 granules

    int bid = blockIdx.x;
    int b = blockIdx.y;
    int lev = (bid < 3) ? 0 : (bid < 15) ? 1 : (bid < 51) ? 2 : (bid < 195) ? 3 : 4;
    int t_ = bid - startB[lev];
    int H = Ht[lev], W = Wt[lev];
    int ty = t_ / tilesX[lev];
    int tx = t_ - ty * tilesX[lev];
    int h0 = ty * 4, w0 = tx * 32;
    const float* x = (lev == 0) ? f0 : (lev == 1) ? f1 : (lev == 2) ? f2 : (lev == 3) ? f3 : f4;
    const float* xb = x + (size_t)b * 256 * H * W;
    int HW = H * W;

    int tid = threadIdx.x;
    int wave = tid >> 6, lane = tid & 63;
    int wm = wave >> 2, wn = wave & 3;
    int nl = lane & 31, hl = lane >> 5;

    f32x16 acc_h[2][2] = {};
    f32x16 acc_l[2][2] = {};

    for (int chunk = 0; chunk < 4; ++chunk) {
        __syncthreads();                 // previous chunk's X readers done
        // stage X halo: 64 ci x 6 rows x 34 cols, fp16 split, plane layout
        for (int e = tid; e < 13056; e += 512) {
            int col = e % 34;
            int r = e / 34;
            int row = r % 6;
            int cl = r / 6;
            int gh = h0 - 1 + row, gw = w0 - 1 + col;
            float v = 0.f;
            if (gh >= 0 && gh < H && gw >= 0 && gw < W)
                v = xb[(chunk * 64 + cl) * HW + gh * W + gw];
            f16 hi = (f16)v;
            f16 lo = (f16)((v - (float)hi) * 2048.0f);
            int base = (((cl >> 3) * 2) * 204 + row * 34 + col) * 8 + (cl & 7);
            Xh[base] = hi;
            Xh[base + 1632] = lo;        // +1 sub plane = 204 granules * 8 f16
        }
        __syncthreads();

        for (int kh = 0; kh < 3; ++kh) {
#pragma unroll
            for (int kw = 0; kw < 3; ++kw)
#pragma unroll
                for (int ks = 0; ks < 4; ++ks) {
                    int cb = ks * 2 + hl;
                    half8 ah[2], al[2], bh[2], bl[2];
#pragma unroll
                    for (int mt = 0; mt < 2; ++mt) {
                        int row = wm * 2 + mt + kh;
                        int gA = (cb * 2) * 204 + row * 34 + nl + kw;
                        ah[mt] = *(const half8*)(Xh + gA * 8);
                        al[mt] = *(const half8*)(Xh + gA * 8 + 1632);
                    }
                    size_t Gbase = ((size_t)(((kh * 3 + kw) * 4 + chunk) * 8 + cb) * 2) * 256;
#pragma unroll
                    for (int nt = 0; nt < 2; ++nt) {
                        int co = wn * 64 + nt * 32 + nl;
                        bh[nt] = *(const half8*)(wsp + (Gbase + co) * 8);
                        bl[nt] = *(const half8*)(wsp + (Gbase + 256 + co) * 8);
                    }
#pragma unroll
                    for (int mt = 0; mt < 2; ++mt)
#pragma unroll
                        for (int nt = 0; nt < 2; ++nt) {
                            acc_h[mt][nt] = __builtin_amdgcn_mfma_f32_32x32x16_f16(
                                ah[mt], bh[nt], acc_h[mt][nt], 0, 0, 0);
                            acc_l[mt][nt] = __builtin_amdgcn_mfma_f32_32x32x16_f16(
                                ah[mt], bl[nt], acc_l[mt][nt], 0, 0, 0);
                            acc_l[mt][nt] = __builtin_amdgcn_mfma_f32_32x32x16_f16(
                                al[mt], bh[nt], acc_l[mt][nt], 0, 0, 0);
                        }
                }
        }
    }

    // ---- fused epilogue, one M-row (32 px) at a time ----
    float* tq = (float*)lds;               // 32 x 260 fp32 = 33280 B
    float* arr = (float*)(lds + 33280);    // 32 x 19 fp32 = 2432 B
    const float sc_h = 1.0f / 128.0f;
    const float sc_l = 1.0f / (128.0f * 2048.0f);
    float cb0 = convb[wn * 64 + nl];
    float cb1 = convb[wn * 64 + 32 + nl];

    for (int MT = 0; MT < 4; ++MT) {
        __syncthreads();
        if (wm == (MT >> 1)) {
            int mt = MT & 1;
#pragma unroll
            for (int nt = 0; nt < 2; ++nt) {
                int co = wn * 64 + nt * 32 + nl;
                float bias = nt ? cb1 : cb0;
#pragma unroll
                for (int r = 0; r < 16; ++r) {
                    int p = (r & 3) + 8 * (r >> 2) + 4 * hl;
                    float v = acc_h[mt][nt][r] * sc_h + acc_l[mt][nt][r] * sc_l + bias;
                    tq[p * 260 + co] = fmaxf(v, 0.f);
                }
            }
        }
        __syncthreads();
        // 1x1 convs: 32 px x 18 ch
        float outv[2];
        int nout = 0;
        for (int oi = tid; oi < 576; oi += 512) {
            int px = oi / 18, ch = oi - px * 18;
            const float* wp = (ch < 6) ? (clsw + ch * 256) : (bbw + (ch - 6) * 256);
            float s = (ch < 6) ? clsb[ch] : bbb[ch - 6];
            const float* trow = tq + px * 260;
            for (int co = 0; co < 256; co += 4) {
                float4 wv = *(const float4*)(wp + co);
                float4 tv = *(const float4*)(trow + co);
                s = fmaf(tv.x, wv.x, s);
                s = fmaf(tv.y, wv.y, s);
                s = fmaf(tv.z, wv.z, s);
                s = fmaf(tv.w, wv.w, s);
            }
            outv[nout++] = s;
        }
        {
            int k = 0;
            for (int oi = tid; oi < 576; oi += 512) {
                int px = oi / 18, ch = oi - px * 18;
                arr[px * 19 + ch] = outv[k++];
            }
        }
        __syncthreads();
        // softmax + decode + clip + filter + key for 32 px x 3 anchors
        if (tid < 96) {
            int px = tid / 3, a = tid - px * 3;
            int w = w0 + px;
            int h = h0 + MT;
            if (w < W) {
                const float* e = &arr[px * 19];
                float l0 = e[a * 2], l1 = e[a * 2 + 1];
                float m = fmaxf(l0, l1);
                float e0 = expf(l0 - m), e1 = expf(l1 - m);
                float score = e1 / (e0 + e1);
                float d0 = e[6 + a * 4 + 0], d1 = e[6 + a * 4 + 1];
                float d2 = e[6 + a * 4 + 2], d3 = e[6 + a * 4 + 3];
                const float wsA[3] = {16.f, 11.f, 9.f};
                const float hsA[3] = {16.f, 22.f, 27.f};
                float aw = wsA[a] * scaleA[lev], ah = hsA[a] * scaleA[lev];
                float ax = 8.f + w * strideA[lev];
                float ay = 8.f + h * strideA[lev];
                float pcx = ax + d0 * aw, pcy = ay + d1 * ah;
                float pw = aw * expf(d2), ph = ah * expf(d3);
                float x1 = pcx - 0.5f * pw, y1 = pcy - 0.5f * ph;
                float x2 = pcx + 0.5f * pw, y2 = pcy + 0.5f * ph;
                float him = im_info[b * 6 + 0], wim = im_info[b * 6 + 1], sim = im_info[b * 6 + 2];
                x1 = fminf(fmaxf(x1, 0.f), wim - 1.f);
                y1 = fminf(fmaxf(y1, 0.f), him - 1.f);
                x2 = fminf(fmaxf(x2, 0.f), wim - 1.f);
                y2 = fminf(fmaxf(y2, 0.f), him - 1.f);
                float thr = 2.f * sim;
                float sc = score;
                if (!((x2 - x1 + 1.f >= thr) && (y2 - y1 + 1.f >= thr))) sc = -1.f;
                u32 u = __float_as_uint(sc);
                u32 okey = u ^ ((u >> 31) ? 0xFFFFFFFFu : 0x80000000u);
                u32 k = ~okey;
                int gi = baseA[lev] + (h * W + w) * 3 + a;
                keys[(size_t)b * NTOT + gi] = k;
                boxes[(size_t)b * NTOT + gi] = make_float4(x1, y1, x2, y2);
            }
        }
    }
}

// ---------------------------------------------------------------------------
// Rank-6000 selection: two-level 11-bit histogram refine on the 32-bit key.
// ---------------------------------------------------------------------------
__global__ __launch_bounds__(256) void hist1_k(const u32* __restrict__ keys,
                                               int* __restrict__ hist) {
    __shared__ int hl[2048];
    int img = blockIdx.y, tid = threadIdx.x;
    for (int i = tid; i < 2048; i += 256) hl[i] = 0;
    __syncthreads();
    int gi = blockIdx.x * 256 + tid;
    if (gi < NTOT) atomicAdd(&hl[keys[(size_t)img * NTOT + gi] >> 21], 1);
    __syncthreads();
    for (int i = tid; i < 2048; i += 256)
        if (hl[i]) atomicAdd(&hist[img * 2048 + i], hl[i]);
}

// LDS two-level scan to find the bin containing rank TOPK (replaces the
// single-thread global-memory scan that cost ~150 us).
__global__ __launch_bounds__(256) void scan1_k(const int* __restrict__ hist,
                                               int* __restrict__ sel) {
    __shared__ int lh[2048];
    __shared__ int seg[256];
    int img = blockIdx.x, tid = threadIdx.x;
    for (int k = 0; k < 8; ++k) lh[tid + k * 256] = hist[img * 2048 + tid + k * 256];
    __syncthreads();
    int s = 0;
    for (int k = 0; k < 8; ++k) s += lh[tid * 8 + k];
    seg[tid] = s;
    __syncthreads();
    if (tid == 0) {
        int cum = 0, b1 = 2047, C1 = 0;
        for (int t = 0; t < 256; ++t) {
            if (cum + seg[t] >= TOPK) {
                for (int k = 0; k < 8; ++k) {
                    int c = lh[t * 8 + k];
                    if (cum + c >= TOPK) { b1 = t * 8 + k; C1 = cum; break; }
                    cum += c;
                }
                break;
            }
            cum += seg[t];
        }
        sel[img * 4 + 0] = b1;
        sel[img * 4 + 1] = C1;
    }
}

__global__ __launch_bounds__(256) void hist2_k(const u32* __restrict__ keys,
                                               const int* __restrict__ sel,
                                               int* __restrict__ hist) {
    __shared__ int hl[2048];
    int img = blockIdx.y, tid = threadIdx.x;
    for (int i = tid; i < 2048; i += 256) hl[i] = 0;
    __syncthreads();
    int b1 = sel[img * 4 + 0];
    int gi = blockIdx.x * 256 + tid;
    if (gi < NTOT) {
        u32 k = keys[(size_t)img * NTOT + gi];
        if ((int)(k >> 21) == b1) atomicAdd(&hl[(k >> 10) & 0x7FF], 1);
    }
    __syncthreads();
    for (int i = tid; i < 2048; i += 256)
        if (hl[i]) atomicAdd(&hist[img * 2048 + i], hl[i]);
}

__global__ __launch_bounds__(256) void scan2_k(const int* __restrict__ hist2,
                                               int* __restrict__ sel) {
    __shared__ int lh[2048];
    __shared__ int seg[256];
    int img = blockIdx.x, tid = threadIdx.x;
    for (int k = 0; k < 8; ++k) lh[tid + k * 256] = hist2[img * 2048 + tid + k * 256];
    __syncthreads();
    int s = 0;
    for (int k = 0; k < 8; ++k) s += lh[tid * 8 + k];
    seg[tid] = s;
    __syncthreads();
    if (tid == 0) {
        int b1 = sel[img * 4 + 0];
        int cum = sel[img * 4 + 1];
        int b2 = 2047;
        for (int t = 0; t < 256; ++t) {
            if (cum + seg[t] >= TOPK) {
                for (int k = 0; k < 8; ++k) {
                    int c = lh[t * 8 + k];
                    if (cum + c >= TOPK) { b2 = t * 8 + k; break; }
                    cum += c;
                }
                break;
            }
            cum += seg[t];
        }
        sel[img * 4 + 2] = (b1 << 11) | b2;  // 22-bit prefix threshold
    }
}

__global__ __launch_bounds__(256) void compact_k(const u32* __restrict__ keys,
                                                 const int* __restrict__ sel,
                                                 int* __restrict__ cnt,
                                                 u64* __restrict__ comp) {
    int img = blockIdx.y;
    int gi = blockIdx.x * 256 + threadIdx.x;
    if (gi >= NTOT) return;
    u32 k = keys[(size_t)img * NTOT + gi];
    if ((int)(k >> 10) <= sel[img * 4 + 2]) {
        int slot = atomicAdd(&cnt[img], 1);
        if (slot < COMPCAP)
            comp[(size_t)img * COMPCAP + slot] = ((u64)k << 32) | (u32)gi;
    }
}

// ---------------------------------------------------------------------------
// Bitonic sort of 8192 (key,idx) u64 in LDS; emit top-6000 boxes/areas/valid.
// ---------------------------------------------------------------------------
__global__ __launch_bounds__(1024) void sort_k(const u64* __restrict__ comp,
                                               const float4* __restrict__ boxes,
                                               float4* __restrict__ tb,
                                               float* __restrict__ areas,
                                               int* __restrict__ validA) {
    __shared__ u64 s[COMPCAP];
    int img = blockIdx.x, tid = threadIdx.x;
    for (int i = tid; i < COMPCAP; i += 1024) s[i] = comp[(size_t)img * COMPCAP + i];
    for (int k = 2; k <= COMPCAP; k <<= 1)
        for (int j = k >> 1; j > 0; j >>= 1) {
            __syncthreads();
            for (int t = tid; t < COMPCAP; t += 1024) {
                int l = t ^ j;
                if (l > t) {
                    u64 a = s[t], bb = s[l];
                    bool up = ((t & k) == 0);
                    if ((a > bb) == up) { s[t] = bb; s[l] = a; }
                }
            }
        }
    __syncthreads();
    for (int r = tid; r < TOPK; r += 1024) {
        u64 kv = s[r];
        u32 idx = (u32)(kv & 0xFFFFFFFFull);
        u32 k32 = (u32)(kv >> 32);
        bool valid = (idx < NTOT) && (k32 != INVALID_KEY);
        float4 bx = valid ? boxes[(size_t)img * NTOT + idx] : make_float4(0.f, 0.f, 0.f, 0.f);
        tb[(size_t)img * TOPK + r] = bx;
        areas[(size_t)img * TOPK + r] = valid ? (bx.z - bx.x + 1.f) * (bx.w - bx.y + 1.f) : 0.f;
        validA[(size_t)img * TOPK + r] = valid ? 1 : 0;
    }
}

// ---------------------------------------------------------------------------
// IoU suppression bitmask: mask[i][wj] bit j set iff iou(i, j) > 0.7
// ---------------------------------------------------------------------------
__global__ __launch_bounds__(256) void mask_k(const float4* __restrict__ tb,
                                              const float* __restrict__ areas,
                                              u64* __restrict__ mask) {
    __shared__ float4 jb[64];
    __shared__ float ja[64];
    int img = blockIdx.z, bi = blockIdx.x, bj = blockIdx.y;
    int tid = threadIdx.x;
    int j0 = bj * 64;
    if (tid < 64) {
        int j = j0 + tid;
        if (j < TOPK) {
            jb[tid] = tb[(size_t)img * TOPK + j];
            ja[tid] = areas[(size_t)img * TOPK + j];
        } else {
            jb[tid] = make_float4(0.f, 0.f, 0.f, 0.f);
            ja[tid] = 0.f;
        }
    }
    __syncthreads();
    int i = bi * 256 + tid;
    if (i >= TOPK) return;
    float4 bb = tb[(size_t)img * TOPK + i];
    float ai = areas[(size_t)img * TOPK + i];
    u64 m = 0;
    int jmax = min(64, TOPK - j0);
    for (int jj = 0; jj < jmax; ++jj) {
        float4 c = jb[jj];
        float ix1 = fmaxf(bb.x, c.x), iy1 = fmaxf(bb.y, c.y);
        float ix2 = fminf(bb.z, c.z), iy2 = fminf(bb.w, c.w);
        float iw = fmaxf(ix2 - ix1 + 1.f, 0.f);
        float ih = fmaxf(iy2 - iy1 + 1.f, 0.f);
        float inter = iw * ih;
        float iou = inter / (ai + ja[jj] - inter);
        if (iou > 0.7f) m |= (1ull << jj);
    }
    mask[(size_t)(img * TOPK + i) * NW + bj] = m;
}

// ---------------------------------------------------------------------------
// Greedy NMS, chunked: winners come in index order, so process 64-box chunks;
// the chunk's 64x94-word mask slab is bulk-prefetched into LDS one chunk
// ahead (global loads overlap the serial phase). Serial phase runs on wave 0
// only: alive bits live in per-lane registers, suppression = LDS reads, no
// global latency in the 1000-iteration critical path.
// ---------------------------------------------------------------------------
__global__ __launch_bounds__(256) void nms_scan_k(const float4* __restrict__ tb,
                                                  const int* __restrict__ validA,
                                                  const u64* __restrict__ mask,
                                                  float* __restrict__ out) {
    __shared__ u64 mbuf[6016];      // 64 rows x 94 words
    __shared__ u64 aliveW[96];
    __shared__ int winL[1000];
    __shared__ int keptS;
    int img = blockIdx.x, tid = threadIdx.x;
    int wv = tid >> 6, lane = tid & 63;
    const u64* mbase = mask + (size_t)img * TOPK * NW;

    if (tid == 0) keptS = 0;
    // alive bitmask via ballot: round k covers indices 256k..256k+255
    for (int k = 0; k < 24; ++k) {
        int idx = 256 * k + tid;
        int v = (idx < TOPK) ? validA[(size_t)img * TOPK + idx] : 0;
        u64 bm = __ballot(v != 0);
        int word = 4 * k + wv;
        if (lane == 0 && word < 94) aliveW[word] = bm;
    }

    u64 regs[24];
    // preload chunk 0
    {
        int avail = 64 * 94;
#pragma unroll
        for (int k = 0; k < 24; ++k) {
            int e = tid + 256 * k;
            regs[k] = (e < avail) ? mbase[e] : 0;
        }
    }
    __syncthreads();
    u64 a0 = 0, a1 = 0;
    if (wv == 0) {
        a0 = aliveW[lane];
        a1 = (lane < 30) ? aliveW[64 + lane] : 0;
    }
    // write chunk 0 to LDS, start loading chunk 1
#pragma unroll
    for (int k = 0; k < 24; ++k) {
        int e = tid + 256 * k;
        if (e < 6016) mbuf[e] = regs[k];
    }
    {
        const u64* slab = mbase + (size_t)64 * 94;
        int avail = 64 * 94;
#pragma unroll
        for (int k = 0; k < 24; ++k) {
            int e = tid + 256 * k;
            if (e < avail) regs[k] = slab[e];
        }
    }
    __syncthreads();

    int kept = 0;
    for (int c = 0; c < 94; ++c) {
        if (wv == 0) {
            u64 wc = (c < 64) ? __shfl(a0, c) : __shfl(a1, c - 64);
            while (wc != 0 && kept < POSTK) {
                int bit = __builtin_ctzll(wc);
                if (lane == 0) winL[kept] = c * 64 + bit;
                ++kept;
                u64 m0 = mbuf[bit * 94 + lane];
                a0 &= ~m0;
                if (lane < 30) {
                    u64 m1 = mbuf[bit * 94 + 64 + lane];
                    a1 &= ~m1;
                }
                wc = (c < 64) ? __shfl(a0, c) : __shfl(a1, c - 64);
            }
            if (lane == 0) keptS = kept;
        }
        __syncthreads();
        if (keptS >= POSTK) break;
        if (c < 93) {
            // commit prefetched chunk c+1 (loads had the serial phase to land)
#pragma unroll
            for (int k = 0; k < 24; ++k) {
                int e = tid + 256 * k;
                if (e < 6016) mbuf[e] = regs[k];
            }
            if (c < 92) {
                int base_row = (c + 2) * 64;
                const u64* slab = mbase + (size_t)base_row * 94;
                int avail = (TOPK - base_row < 64 ? TOPK - base_row : 64) * 94;
#pragma unroll
                for (int k = 0; k < 24; ++k) {
                    int e = tid + 256 * k;
                    if (e < avail) regs[k] = slab[e];
                }
            }
            __syncthreads();
        }
    }

    __syncthreads();
    int kf = keptS < POSTK ? keptS : POSTK;
    for (int r = tid; r < kf; r += 256) {
        int i = winL[r];
        float4 bx = tb[(size_t)img * TOPK + i];
        float* o = out + ((size_t)img * POSTK + r) * 5;
        o[0] = (float)img; o[1] = bx.x; o[2] = bx.y; o[3] = bx.z; o[4] = bx.w;
    }
}

// ---------------------------------------------------------------------------
extern "C" void kernel_launch(void* const* d_in, const int* in_sizes, int n_in,
                              void* d_out, int out_size, void* d_ws, size_t ws_size,
                              hipStream_t stream) {
    const float* f0 = (const float*)d_in[0];
    const float* f1 = (const float*)d_in[1];
    const float* f2 = (const float*)d_in[2];
    const float* f3 = (const float*)d_in[3];
    const float* f4 = (const float*)d_in[4];
    const float* convw = (const float*)d_in[5];
    const float* convb = (const float*)d_in[6];
    const float* clsw = (const float*)d_in[7];
    const float* clsb = (const float*)d_in[8];
    const float* bbw = (const float*)d_in[9];
    const float* bbb = (const float*)d_in[10];
    const float* iminfo = (const float*)d_in[11];

    char* ws = (char*)d_ws;
    size_t off = 0;
    auto alloc = [&](size_t bytes) -> void* {
        void* p = ws + off;
        off = (off + bytes + 255) & ~(size_t)255;
        return p;
    };
    f16* wsp = (f16*)alloc((size_t)1179648 * 2);  // split weights, granule layout
    u32* keys = (u32*)alloc((size_t)2 * NTOT * 4);
    float4* boxes = (float4*)alloc((size_t)2 * NTOT * 16);
    int* zr = (int*)alloc(2 * 2048 * 4 + 2 * 2048 * 4 + 32 + 8);
    int* hist1 = zr;
    int* hist2 = zr + 2 * 2048;
    int* sel = hist2 + 2 * 2048;
    int* cnt = sel + 8;
    u64* comp = (u64*)alloc((size_t)2 * COMPCAP * 8);
    float4* tb = (float4*)alloc((size_t)2 * TOPK * 16);
    float* areas = (float*)alloc((size_t)2 * TOPK * 4);
    int* validA = (int*)alloc((size_t)2 * TOPK * 4);
    u64* mask = (u64*)alloc((size_t)2 * TOPK * NW * 8);

    hipMemsetAsync(zr, 0, 2 * 2048 * 4 + 2 * 2048 * 4 + 32 + 8, stream);
    hipMemsetAsync(comp, 0xFF, (size_t)2 * COMPCAP * 8, stream);
    hipMemsetAsync(d_out, 0, (size_t)out_size * 4, stream);

    wtrans_k<<<dim3(2304), 256, 0, stream>>>(convw, wsp);
    conv_mfma_k<<<dim3(723, 2), 512, 0, stream>>>(f0, f1, f2, f3, f4, wsp, convb,
                                                  clsw, clsb, bbw, bbb, iminfo,
                                                  keys, boxes);
    hist1_k<<<dim3(1055, 2), 256, 0, stream>>>(keys, hist1);
    scan1_k<<<2, 256, 0, stream>>>(hist1, sel);
    hist2_k<<<dim3(1055, 2), 256, 0, stream>>>(keys, sel, hist2);
    scan2_k<<<2, 256, 0, stream>>>(hist2, sel);
    compact_k<<<dim3(1055, 2), 256, 0, stream>>>(keys, sel, cnt, comp);
    sort_k<<<2, 1024, 0, stream>>>(comp, boxes, tb, areas, validA);
    mask_k<<<dim3(24, NW, 2), 256, 0, stream>>>(tb, areas, mask);
    nms_scan_k<<<2, 256, 0, stream>>>(tb, validA, mask, (float*)d_out);
}

// Round 6
// 1802.339 us; speedup vs baseline: 5.3789x; 5.3789x over previous
//
#include <hip/hip_runtime.h>
#include <stdint.h>

typedef unsigned long long u64;
typedef unsigned int u32;
typedef _Float16 f16;
typedef _Float16 half2v __attribute__((ext_vector_type(2)));
typedef _Float16 half8 __attribute__((ext_vector_type(8)));
typedef float f32x16 __attribute__((ext_vector_type(16)));

#define NTOT 270072
#define TOPK 6000
#define POSTK 1000
#define NW 94              // ceil(6000/64)
#define COMPCAP 8192
#define INVALID_KEY 0xBF800000u

// ---------------------------------------------------------------------------
// Weight transform + fp16x2 split. Input convw OIHW [co][ci][3][3] fp32.
// Output wsp 16B-granule layout: G = (((tap*4 + chunk64)*8 + cb)*2 + half)*256 + co,
// cb = (ci>>3)&7, j = ci&7 inside the granule. conv loads B-fragments straight
// from global (L2-resident, 2.36 MB), so W never touches LDS.
// Weights pre-scaled x128 so lo-halves stay fp16-normal; epilogue /128.
// ---------------------------------------------------------------------------
__global__ __launch_bounds__(256) void wtrans_k(const float* __restrict__ w3,
                                                f16* __restrict__ wsp) {
    int i = blockIdx.x * 256 + threadIdx.x;   // coalesced read of w3
    if (i >= 589824) return;
    float w = w3[i] * 128.0f;
    int tap = i % 9;
    int t2 = i / 9;
    int ci = t2 % 256;
    int co = t2 / 256;
    f16 hi = (f16)w;
    f16 lo = (f16)((w - (float)hi) * 2048.0f);
    int chunk = ci >> 6, cb = (ci >> 3) & 7, j = ci & 7;
    size_t Gh = ((size_t)((tap * 4 + chunk) * 8 + cb) * 2) * 256 + co;
    wsp[Gh * 8 + j] = hi;
    wsp[(Gh + 256) * 8 + j] = lo;   // half=1 plane
}

// ---------------------------------------------------------------------------
// MFMA implicit-GEMM conv (fp16x2 split, 3 products) + fused epilogue.
// Block: 512 thr (8 waves), tile M=128 px (4 h-rows x 32 w) x N=256 co.
// LDS: X halo only, one 64-ci chunk: granule gx = sub*204 + row*34 + col,
//      sub = cb*2+half in [0,16)  -> 16*204*16 B = 52224 B.
// B-fragments are loaded global->VGPR per K-step (coalesced 16B/lane, hits
// L2). Barriers ONLY around the 4 X-stages; 432 MFMAs run barrier-free per
// chunk so the compiler can vmcnt-pipeline the streaming B loads.
// __launch_bounds__(512,2): 256-reg budget. Accumulators (8 x f32x16 = 128
// AGPR) + ~112 VGPR must fit; (512,4) in R5 forced the acc tile into scratch
// (41 GB HBM spill traffic, 6x regression). DO NOT raise the min-waves arg.
// ---------------------------------------------------------------------------
__global__ __launch_bounds__(512, 2) void conv_mfma_k(
    const float* __restrict__ f0, const float* __restrict__ f1,
    const float* __restrict__ f2, const float* __restrict__ f3,
    const float* __restrict__ f4,
    const f16* __restrict__ wsp, const float* __restrict__ convb,
    const float* __restrict__ clsw, const float* __restrict__ clsb,
    const float* __restrict__ bbw, const float* __restrict__ bbb,
    const float* __restrict__ im_info,
    u32* __restrict__ keys, float4* __restrict__ boxes)
{
    const int   Ht[5]      = {12, 24, 48, 96, 192};
    const int   Wt[5]      = {22, 44, 88, 176, 352};
    const int   startB[5]  = {0, 3, 15, 51, 195};
    const int   tilesX[5]  = {1, 2, 3, 6, 11};
    const int   baseA[5]   = {0, 792, 3960, 16632, 67320};
    const float scaleA[5]  = {32.f, 16.f, 8.f, 4.f, 2.f};
    const float strideA[5] = {64.f, 32.f, 16.f, 8.f, 4.f};

    __shared__ __align__(16) char lds[52224];
    f16* Xh = (f16*)lds;                      // 16 sub-planes x 204 granules

    int bid = blockIdx.x;
    int b = blockIdx.y;
    int lev = (bid < 3) ? 0 : (bid < 15) ? 1 : (bid < 51) ? 2 : (bid < 195) ? 3 : 4;
    int t_ = bid - startB[lev];
    int H = Ht[lev], W = Wt[lev];
    int ty = t_ / tilesX[lev];
    int tx = t_ - ty * tilesX[lev];
    int h0 = ty * 4, w0 = tx * 32;
    const float* x = (lev == 0) ? f0 : (lev == 1) ? f1 : (lev == 2) ? f2 : (lev == 3) ? f3 : f4;
    const float* xb = x + (size_t)b * 256 * H * W;
    int HW = H * W;

    int tid = threadIdx.x;
    int wave = tid >> 6, lane = tid & 63;
    int wm = wave >> 2, wn = wave & 3;
    int nl = lane & 31, hl = lane >> 5;

    f32x16 acc_h[2][2] = {};
    f32x16 acc_l[2][2] = {};

    for (int chunk = 0; chunk < 4; ++chunk) {
        __syncthreads();                 // previous chunk's X readers done
        // stage X halo: 64 ci x 6 rows x 34 cols, fp16 split, plane layout.
        // Each iteration handles a ci-PAIR so stores are 4B ds_write_b32.
        for (int e = tid; e < 6528; e += 512) {
            int col = e % 34;
            int r = e / 34;
            int row = r % 6;
            int clp = r / 6;             // ci pair index 0..31
            int cl = clp * 2;
            int gh = h0 - 1 + row, gw = w0 - 1 + col;
            float v0 = 0.f, v1 = 0.f;
            if (gh >= 0 && gh < H && gw >= 0 && gw < W) {
                const float* p = xb + (size_t)(chunk * 64 + cl) * HW + gh * W + gw;
                v0 = p[0];
                v1 = p[HW];
            }
            f16 h0f = (f16)v0, h1f = (f16)v1;
            f16 l0f = (f16)((v0 - (float)h0f) * 2048.0f);
            f16 l1f = (f16)((v1 - (float)h1f) * 2048.0f);
            int fi = (((cl >> 3) * 2) * 204 + row * 34 + col) * 8 + (cl & 7);
            half2v hv = {h0f, h1f};
            half2v lv = {l0f, l1f};
            *(half2v*)(Xh + fi) = hv;
            *(half2v*)(Xh + fi + 1632) = lv;   // +1 sub plane = 204 granules
        }
        __syncthreads();

        for (int kh = 0; kh < 3; ++kh) {
#pragma unroll
            for (int kw = 0; kw < 3; ++kw)
#pragma unroll
                for (int ks = 0; ks < 4; ++ks) {
                    int cb = ks * 2 + hl;
                    half8 ah[2], al[2], bh[2], bl[2];
#pragma unroll
                    for (int mt = 0; mt < 2; ++mt) {
                        int row = wm * 2 + mt + kh;
                        int gA = (cb * 2) * 204 + row * 34 + nl + kw;
                        ah[mt] = *(const half8*)(Xh + gA * 8);
                        al[mt] = *(const half8*)(Xh + gA * 8 + 1632);
                    }
                    size_t Gbase = ((size_t)(((kh * 3 + kw) * 4 + chunk) * 8 + cb) * 2) * 256;
#pragma unroll
                    for (int nt = 0; nt < 2; ++nt) {
                        int co = wn * 64 + nt * 32 + nl;
                        bh[nt] = *(const half8*)(wsp + (Gbase + co) * 8);
                        bl[nt] = *(const half8*)(wsp + (Gbase + 256 + co) * 8);
                    }
#pragma unroll
                    for (int mt = 0; mt < 2; ++mt)
#pragma unroll
                        for (int nt = 0; nt < 2; ++nt) {
                            acc_h[mt][nt] = __builtin_amdgcn_mfma_f32_32x32x16_f16(
                                ah[mt], bh[nt], acc_h[mt][nt], 0, 0, 0);
                            acc_l[mt][nt] = __builtin_amdgcn_mfma_f32_32x32x16_f16(
                                ah[mt], bl[nt], acc_l[mt][nt], 0, 0, 0);
                            acc_l[mt][nt] = __builtin_amdgcn_mfma_f32_32x32x16_f16(
                                al[mt], bh[nt], acc_l[mt][nt], 0, 0, 0);
                        }
                }
        }
    }

    // ---- fused epilogue, one M-row (32 px) at a time ----
    float* tq = (float*)lds;               // 32 x 260 fp32 = 33280 B
    float* arr = (float*)(lds + 33280);    // 32 x 19 fp32 = 2432 B
    const float sc_h = 1.0f / 128.0f;
    const float sc_l = 1.0f / (128.0f * 2048.0f);
    float cb0 = convb[wn * 64 + nl];
    float cb1 = convb[wn * 64 + 32 + nl];

    for (int MT = 0; MT < 4; ++MT) {
        __syncthreads();
        if (wm == (MT >> 1)) {
            int mt = MT & 1;
#pragma unroll
            for (int nt = 0; nt < 2; ++nt) {
                int co = wn * 64 + nt * 32 + nl;
                float bias = nt ? cb1 : cb0;
#pragma unroll
                for (int r = 0; r < 16; ++r) {
                    int p = (r & 3) + 8 * (r >> 2) + 4 * hl;
                    float v = acc_h[mt][nt][r] * sc_h + acc_l[mt][nt][r] * sc_l + bias;
                    tq[p * 260 + co] = fmaxf(v, 0.f);
                }
            }
        }
        __syncthreads();
        // 1x1 convs: 32 px x 18 ch
        float outv[2];
        int nout = 0;
        for (int oi = tid; oi < 576; oi += 512) {
            int px = oi / 18, ch = oi - px * 18;
            const float* wp = (ch < 6) ? (clsw + ch * 256) : (bbw + (ch - 6) * 256);
            float s = (ch < 6) ? clsb[ch] : bbb[ch - 6];
            const float* trow = tq + px * 260;
            for (int co = 0; co < 256; co += 4) {
                float4 wv = *(const float4*)(wp + co);
                float4 tv = *(const float4*)(trow + co);
                s = fmaf(tv.x, wv.x, s);
                s = fmaf(tv.y, wv.y, s);
                s = fmaf(tv.z, wv.z, s);
                s = fmaf(tv.w, wv.w, s);
            }
            outv[nout++] = s;
        }
        {
            int k = 0;
            for (int oi = tid; oi < 576; oi += 512) {
                int px = oi / 18, ch = oi - px * 18;
                arr[px * 19 + ch] = outv[k++];
            }
        }
        __syncthreads();
        // softmax + decode + clip + filter + key for 32 px x 3 anchors
        if (tid < 96) {
            int px = tid / 3, a = tid - px * 3;
            int w = w0 + px;
            int h = h0 + MT;
            if (w < W) {
                const float* e = &arr[px * 19];
                float l0 = e[a * 2], l1 = e[a * 2 + 1];
                float m = fmaxf(l0, l1);
                float e0 = expf(l0 - m), e1 = expf(l1 - m);
                float score = e1 / (e0 + e1);
                float d0 = e[6 + a * 4 + 0], d1 = e[6 + a * 4 + 1];
                float d2 = e[6 + a * 4 + 2], d3 = e[6 + a * 4 + 3];
                const float wsA[3] = {16.f, 11.f, 9.f};
                const float hsA[3] = {16.f, 22.f, 27.f};
                float aw = wsA[a] * scaleA[lev], ah = hsA[a] * scaleA[lev];
                float ax = 8.f + w * strideA[lev];
                float ay = 8.f + h * strideA[lev];
                float pcx = ax + d0 * aw, pcy = ay + d1 * ah;
                float pw = aw * expf(d2), ph = ah * expf(d3);
                float x1 = pcx - 0.5f * pw, y1 = pcy - 0.5f * ph;
                float x2 = pcx + 0.5f * pw, y2 = pcy + 0.5f * ph;
                float him = im_info[b * 6 + 0], wim = im_info[b * 6 + 1], sim = im_info[b * 6 + 2];
                x1 = fminf(fmaxf(x1, 0.f), wim - 1.f);
                y1 = fminf(fmaxf(y1, 0.f), him - 1.f);
                x2 = fminf(fmaxf(x2, 0.f), wim - 1.f);
                y2 = fminf(fmaxf(y2, 0.f), him - 1.f);
                float thr = 2.f * sim;
                float sc = score;
                if (!((x2 - x1 + 1.f >= thr) && (y2 - y1 + 1.f >= thr))) sc = -1.f;
                u32 u = __float_as_uint(sc);
                u32 okey = u ^ ((u >> 31) ? 0xFFFFFFFFu : 0x80000000u);
                u32 k = ~okey;
                int gi = baseA[lev] + (h * W + w) * 3 + a;
                keys[(size_t)b * NTOT + gi] = k;
                boxes[(size_t)b * NTOT + gi] = make_float4(x1, y1, x2, y2);
            }
        }
    }
}

// ---------------------------------------------------------------------------
// Rank-6000 selection: two-level 11-bit histogram refine on the 32-bit key.
// ---------------------------------------------------------------------------
__global__ __launch_bounds__(256) void hist1_k(const u32* __restrict__ keys,
                                               int* __restrict__ hist) {
    __shared__ int hl[2048];
    int img = blockIdx.y, tid = threadIdx.x;
    for (int i = tid; i < 2048; i += 256) hl[i] = 0;
    __syncthreads();
    int gi = blockIdx.x * 256 + tid;
    if (gi < NTOT) atomicAdd(&hl[keys[(size_t)img * NTOT + gi] >> 21], 1);
    __syncthreads();
    for (int i = tid; i < 2048; i += 256)
        if (hl[i]) atomicAdd(&hist[img * 2048 + i], hl[i]);
}

// LDS two-level scan to find the bin containing rank TOPK.
__global__ __launch_bounds__(256) void scan1_k(const int* __restrict__ hist,
                                               int* __restrict__ sel) {
    __shared__ int lh[2048];
    __shared__ int seg[256];
    int img = blockIdx.x, tid = threadIdx.x;
    for (int k = 0; k < 8; ++k) lh[tid + k * 256] = hist[img * 2048 + tid + k * 256];
    __syncthreads();
    int s = 0;
    for (int k = 0; k < 8; ++k) s += lh[tid * 8 + k];
    seg[tid] = s;
    __syncthreads();
    if (tid == 0) {
        int cum = 0, b1 = 2047, C1 = 0;
        for (int t = 0; t < 256; ++t) {
            if (cum + seg[t] >= TOPK) {
                for (int k = 0; k < 8; ++k) {
                    int c = lh[t * 8 + k];
                    if (cum + c >= TOPK) { b1 = t * 8 + k; C1 = cum; break; }
                    cum += c;
                }
                break;
            }
            cum += seg[t];
        }
        sel[img * 4 + 0] = b1;
        sel[img * 4 + 1] = C1;
    }
}

__global__ __launch_bounds__(256) void hist2_k(const u32* __restrict__ keys,
                                               const int* __restrict__ sel,
                                               int* __restrict__ hist) {
    __shared__ int hl[2048];
    int img = blockIdx.y, tid = threadIdx.x;
    for (int i = tid; i < 2048; i += 256) hl[i] = 0;
    __syncthreads();
    int b1 = sel[img * 4 + 0];
    int gi = blockIdx.x * 256 + tid;
    if (gi < NTOT) {
        u32 k = keys[(size_t)img * NTOT + gi];
        if ((int)(k >> 21) == b1) atomicAdd(&hl[(k >> 10) & 0x7FF], 1);
    }
    __syncthreads();
    for (int i = tid; i < 2048; i += 256)
        if (hl[i]) atomicAdd(&hist[img * 2048 + i], hl[i]);
}

__global__ __launch_bounds__(256) void scan2_k(const int* __restrict__ hist2,
                                               int* __restrict__ sel) {
    __shared__ int lh[2048];
    __shared__ int seg[256];
    int img = blockIdx.x, tid = threadIdx.x;
    for (int k = 0; k < 8; ++k) lh[tid + k * 256] = hist2[img * 2048 + tid + k * 256];
    __syncthreads();
    int s = 0;
    for (int k = 0; k < 8; ++k) s += lh[tid * 8 + k];
    seg[tid] = s;
    __syncthreads();
    if (tid == 0) {
        int b1 = sel[img * 4 + 0];
        int cum = sel[img * 4 + 1];
        int b2 = 2047;
        for (int t = 0; t < 256; ++t) {
            if (cum + seg[t] >= TOPK) {
                for (int k = 0; k < 8; ++k) {
                    int c = lh[t * 8 + k];
                    if (cum + c >= TOPK) { b2 = t * 8 + k; break; }
                    cum += c;
                }
                break;
            }
            cum += seg[t];
        }
        sel[img * 4 + 2] = (b1 << 11) | b2;  // 22-bit prefix threshold
    }
}

__global__ __launch_bounds__(256) void compact_k(const u32* __restrict__ keys,
                                                 const int* __restrict__ sel,
                                                 int* __restrict__ cnt,
                                                 u64* __restrict__ comp) {
    int img = blockIdx.y;
    int gi = blockIdx.x * 256 + threadIdx.x;
    if (gi >= NTOT) return;
    u32 k = keys[(size_t)img * NTOT + gi];
    if ((int)(k >> 10) <= sel[img * 4 + 2]) {
        int slot = atomicAdd(&cnt[img], 1);
        if (slot < COMPCAP)
            comp[(size_t)img * COMPCAP + slot] = ((u64)k << 32) | (u32)gi;
    }
}

// ---------------------------------------------------------------------------
// Bitonic sort of 8192 (key,idx) u64 in LDS; emit top-6000 boxes/areas/valid.
// ---------------------------------------------------------------------------
__global__ __launch_bounds__(1024) void sort_k(const u64* __restrict__ comp,
                                               const float4* __restrict__ boxes,
                                               float4* __restrict__ tb,
                                               float* __restrict__ areas,
                                               int* __restrict__ validA) {
    __shared__ u64 s[COMPCAP];
    int img = blockIdx.x, tid = threadIdx.x;
    for (int i = tid; i < COMPCAP; i += 1024) s[i] = comp[(size_t)img * COMPCAP + i];
    for (int k = 2; k <= COMPCAP; k <<= 1)
        for (int j = k >> 1; j > 0; j >>= 1) {
            __syncthreads();
            for (int t = tid; t < COMPCAP; t += 1024) {
                int l = t ^ j;
                if (l > t) {
                    u64 a = s[t], bb = s[l];
                    bool up = ((t & k) == 0);
                    if ((a > bb) == up) { s[t] = bb; s[l] = a; }
                }
            }
        }
    __syncthreads();
    for (int r = tid; r < TOPK; r += 1024) {
        u64 kv = s[r];
        u32 idx = (u32)(kv & 0xFFFFFFFFull);
        u32 k32 = (u32)(kv >> 32);
        bool valid = (idx < NTOT) && (k32 != INVALID_KEY);
        float4 bx = valid ? boxes[(size_t)img * NTOT + idx] : make_float4(0.f, 0.f, 0.f, 0.f);
        tb[(size_t)img * TOPK + r] = bx;
        areas[(size_t)img * TOPK + r] = valid ? (bx.z - bx.x + 1.f) * (bx.w - bx.y + 1.f) : 0.f;
        validA[(size_t)img * TOPK + r] = valid ? 1 : 0;
    }
}

// ---------------------------------------------------------------------------
// IoU suppression bitmask: mask[i][wj] bit j set iff iou(i, j) > 0.7
// ---------------------------------------------------------------------------
__global__ __launch_bounds__(256) void mask_k(const float4* __restrict__ tb,
                                              const float* __restrict__ areas,
                                              u64* __restrict__ mask) {
    __shared__ float4 jb[64];
    __shared__ float ja[64];
    int img = blockIdx.z, bi = blockIdx.x, bj = blockIdx.y;
    int tid = threadIdx.x;
    int j0 = bj * 64;
    if (tid < 64) {
        int j = j0 + tid;
        if (j < TOPK) {
            jb[tid] = tb[(size_t)img * TOPK + j];
            ja[tid] = areas[(size_t)img * TOPK + j];
        } else {
            jb[tid] = make_float4(0.f, 0.f, 0.f, 0.f);
            ja[tid] = 0.f;
        }
    }
    __syncthreads();
    int i = bi * 256 + tid;
    if (i >= TOPK) return;
    float4 bb = tb[(size_t)img * TOPK + i];
    float ai = areas[(size_t)img * TOPK + i];
    u64 m = 0;
    int jmax = min(64, TOPK - j0);
    for (int jj = 0; jj < jmax; ++jj) {
        float4 c = jb[jj];
        float ix1 = fmaxf(bb.x, c.x), iy1 = fmaxf(bb.y, c.y);
        float ix2 = fminf(bb.z, c.z), iy2 = fminf(bb.w, c.w);
        float iw = fmaxf(ix2 - ix1 + 1.f, 0.f);
        float ih = fmaxf(iy2 - iy1 + 1.f, 0.f);
        float inter = iw * ih;
        float iou = inter / (ai + ja[jj] - inter);
        if (iou > 0.7f) m |= (1ull << jj);
    }
    mask[(size_t)(img * TOPK + i) * NW + bj] = m;
}

// ---------------------------------------------------------------------------
// Greedy NMS, chunked: winners come in index order, so process 64-box chunks;
// the chunk's 64x94-word mask slab is bulk-prefetched into LDS one chunk
// ahead. Serial phase runs on wave 0 only: alive bits in per-lane registers,
// suppression = LDS reads + shfl, no global latency in the critical path.
// ---------------------------------------------------------------------------
__global__ __launch_bounds__(256) void nms_scan_k(const float4* __restrict__ tb,
                                                  const int* __restrict__ validA,
                                                  const u64* __restrict__ mask,
                                                  float* __restrict__ out) {
    __shared__ u64 mbuf[6016];      // 64 rows x 94 words
    __shared__ u64 aliveW[96];
    __shared__ int winL[1000];
    __shared__ int keptS;
    int img = blockIdx.x, tid = threadIdx.x;
    int wv = tid >> 6, lane = tid & 63;
    const u64* mbase = mask + (size_t)img * TOPK * NW;

    if (tid == 0) keptS = 0;
    // alive bitmask via ballot: round k covers indices 256k..256k+255
    for (int k = 0; k < 24; ++k) {
        int idx = 256 * k + tid;
        int v = (idx < TOPK) ? validA[(size_t)img * TOPK + idx] : 0;
        u64 bm = __ballot(v != 0);
        int word = 4 * k + wv;
        if (lane == 0 && word < 94) aliveW[word] = bm;
    }

    u64 regs[24];
    // preload chunk 0
    {
        int avail = 64 * 94;
#pragma unroll
        for (int k = 0; k < 24; ++k) {
            int e = tid + 256 * k;
            regs[k] = (e < avail) ? mbase[e] : 0;
        }
    }
    __syncthreads();
    u64 a0 = 0, a1 = 0;
    if (wv == 0) {
        a0 = aliveW[lane];
        a1 = (lane < 30) ? aliveW[64 + lane] : 0;
    }
    // write chunk 0 to LDS, start loading chunk 1
#pragma unroll
    for (int k = 0; k < 24; ++k) {
        int e = tid + 256 * k;
        if (e < 6016) mbuf[e] = regs[k];
    }
    {
        const u64* slab = mbase + (size_t)64 * 94;
        int avail = 64 * 94;
#pragma unroll
        for (int k = 0; k < 24; ++k) {
            int e = tid + 256 * k;
            if (e < avail) regs[k] = slab[e];
        }
    }
    __syncthreads();

    int kept = 0;
    for (int c = 0; c < 94; ++c) {
        if (wv == 0) {
            u64 wc = (c < 64) ? __shfl(a0, c) : __shfl(a1, c - 64);
            while (wc != 0 && kept < POSTK) {
                int bit = __builtin_ctzll(wc);
                if (lane == 0) winL[kept] = c * 64 + bit;
                ++kept;
                u64 m0 = mbuf[bit * 94 + lane];
                a0 &= ~m0;
                if (lane < 30) {
                    u64 m1 = mbuf[bit * 94 + 64 + lane];
                    a1 &= ~m1;
                }
                wc = (c < 64) ? __shfl(a0, c) : __shfl(a1, c - 64);
            }
            if (lane == 0) keptS = kept;
        }
        __syncthreads();
        if (keptS >= POSTK) break;
        if (c < 93) {
            // commit prefetched chunk c+1 (loads had the serial phase to land)
#pragma unroll
            for (int k = 0; k < 24; ++k) {
                int e = tid + 256 * k;
                if (e < 6016) mbuf[e] = regs[k];
            }
            if (c < 92) {
                int base_row = (c + 2) * 64;
                const u64* slab = mbase + (size_t)base_row * 94;
                int avail = (TOPK - base_row < 64 ? TOPK - base_row : 64) * 94;
#pragma unroll
                for (int k = 0; k < 24; ++k) {
                    int e = tid + 256 * k;
                    if (e < avail) regs[k] = slab[e];
                }
            }
            __syncthreads();
        }
    }

    __syncthreads();
    int kf = keptS < POSTK ? keptS : POSTK;
    for (int r = tid; r < kf; r += 256) {
        int i = winL[r];
        float4 bx = tb[(size_t)img * TOPK + i];
        float* o = out + ((size_t)img * POSTK + r) * 5;
        o[0] = (float)img; o[1] = bx.x; o[2] = bx.y; o[3] = bx.z; o[4] = bx.w;
    }
}

// ---------------------------------------------------------------------------
extern "C" void kernel_launch(void* const* d_in, const int* in_sizes, int n_in,
                              void* d_out, int out_size, void* d_ws, size_t ws_size,
                              hipStream_t stream) {
    const float* f0 = (const float*)d_in[0];
    const float* f1 = (const float*)d_in[1];
    const float* f2 = (const float*)d_in[2];
    const float* f3 = (const float*)d_in[3];
    const float* f4 = (const float*)d_in[4];
    const float* convw = (const float*)d_in[5];
    const float* convb = (const float*)d_in[6];
    const float* clsw = (const float*)d_in[7];
    const float* clsb = (const float*)d_in[8];
    const float* bbw = (const float*)d_in[9];
    const float* bbb = (const float*)d_in[10];
    const float* iminfo = (const float*)d_in[11];

    char* ws = (char*)d_ws;
    size_t off = 0;
    auto alloc = [&](size_t bytes) -> void* {
        void* p = ws + off;
        off = (off + bytes + 255) & ~(size_t)255;
        return p;
    };
    f16* wsp = (f16*)alloc((size_t)1179648 * 2);  // split weights, granule layout
    u32* keys = (u32*)alloc((size_t)2 * NTOT * 4);
    float4* boxes = (float4*)alloc((size_t)2 * NTOT * 16);
    int* zr = (int*)alloc(2 * 2048 * 4 + 2 * 2048 * 4 + 32 + 8);
    int* hist1 = zr;
    int* hist2 = zr + 2 * 2048;
    int* sel = hist2 + 2 * 2048;
    int* cnt = sel + 8;
    u64* comp = (u64*)alloc((size_t)2 * COMPCAP * 8);
    float4* tb = (float4*)alloc((size_t)2 * TOPK * 16);
    float* areas = (float*)alloc((size_t)2 * TOPK * 4);
    int* validA = (int*)alloc((size_t)2 * TOPK * 4);
    u64* mask = (u64*)alloc((size_t)2 * TOPK * NW * 8);

    hipMemsetAsync(zr, 0, 2 * 2048 * 4 + 2 * 2048 * 4 + 32 + 8, stream);
    hipMemsetAsync(comp, 0xFF, (size_t)2 * COMPCAP * 8, stream);
    hipMemsetAsync(d_out, 0, (size_t)out_size * 4, stream);

    wtrans_k<<<dim3(2304), 256, 0, stream>>>(convw, wsp);
    conv_mfma_k<<<dim3(723, 2), 512, 0, stream>>>(f0, f1, f2, f3, f4, wsp, convb,
                                                  clsw, clsb, bbw, bbb, iminfo,
                                                  keys, boxes);
    hist1_k<<<dim3(1055, 2), 256, 0, stream>>>(keys, hist1);
    scan1_k<<<2, 256, 0, stream>>>(hist1, sel);
    hist2_k<<<dim3(1055, 2), 256, 0, stream>>>(keys, sel, hist2);
    scan2_k<<<2, 256, 0, stream>>>(hist2, sel);
    compact_k<<<dim3(1055, 2), 256, 0, stream>>>(keys, sel, cnt, comp);
    sort_k<<<2, 1024, 0, stream>>>(comp, boxes, tb, areas, validA);
    mask_k<<<dim3(24, NW, 2), 256, 0, stream>>>(tb, areas, mask);
    nms_scan_k<<<2, 256, 0, stream>>>(tb, validA, mask, (float*)d_out);
}